// Round 11
// baseline (30.748 us; speedup 1.0000x reference)
//
#include <hip/hip_runtime.h>
#include <math.h>

#define HW2   196      // 14*14
#define IMG   224
#define IMG2  (224*224)
#define SPB   2        // strips per block (staged to LDS)
#define STAGEF (SPB*16*IMG)   // 7168 floats = 28672 bytes per block

typedef float f32x4 __attribute__((ext_vector_type(4)));

// ---------------- K1: LDS-staged patch means ----------------
// Block = 256 thr (4 waves), covers 2 contiguous strips = 28672 contiguous
// bytes of input. Stage via global_load_lds width=16 (7 ops/thread, zero
// VGPR cost -> ~100KB/CU in flight, HBM-BW-bound instead of VGPR-MLP-bound).
// Then wave w reduces strip w>>1 rows (w&1)*8..+7 from LDS (contiguous
// ds_read_b128, conflict-free), 3 shuffles -> per-patch half sums -> LDS;
// wave 0 combines, writes 28 means + block {min,max,sum} partial.
__global__ __launch_bounds__(256) void k_patch_mean(const float* __restrict__ in,
                                                    float* __restrict__ resized,
                                                    float* __restrict__ pmin,
                                                    float* __restrict__ pmax,
                                                    float* __restrict__ psum) {
    __shared__ float smem[STAGEF];
    __shared__ float halfsums[4][14];

    const int t    = threadIdx.x;
    const int wid  = t >> 6;
    const int lane = t & 63;

    // ---- stage 28672B: op i, wave w -> 1024B chunk (i*4+w), lane-linear ----
    const float* gsrc = in + (size_t)blockIdx.x * STAGEF;
    #pragma unroll
    for (int i = 0; i < 7; ++i) {
        int chunk = i * 4 + wid;                 // 0..27, wave-uniform
        const float* gp = gsrc + chunk * 256 + lane * 4;   // per-lane 16B
        float* lp = smem + chunk * 256;          // wave-uniform LDS base
        __builtin_amdgcn_global_load_lds(gp, lp, 16, 0, 0);
    }
    __syncthreads();

    // ---- reduce: wave w -> strip (w>>1), rows (w&1)*8 .. +7 ----
    const int sl = wid >> 1;
    const int r0 = (wid & 1) * 8;
    f32x4 acc = (f32x4)(0.f);
    if (lane < 56) {
        const f32x4* base = (const f32x4*)(smem + sl * (16 * IMG)) + lane;
        #pragma unroll
        for (int r = 0; r < 8; ++r) acc += base[(r0 + r) * 56];
    }
    float h = (acc.x + acc.y) + (acc.z + acc.w);
    h += __shfl_xor(h, 1, 64);
    h += __shfl_xor(h, 2, 64);                   // lane 4p: half-sum of patch p
    if (lane < 56 && (lane & 3) == 0) halfsums[wid][lane >> 2] = h;
    __syncthreads();

    if (wid == 0) {
        float mnv = INFINITY, mxv = -INFINITY, sv = 0.0f;
        if (lane < SPB * 14) {
            int s2 = lane / 14, p = lane - s2 * 14;
            float mean = (halfsums[2 * s2][p] + halfsums[2 * s2 + 1][p])
                         * (1.0f / 256.0f);
            resized[blockIdx.x * (SPB * 14) + lane] = mean;
            mnv = mean; mxv = mean; sv = mean;
        }
        #pragma unroll
        for (int off = 32; off; off >>= 1) {
            mnv = fminf(mnv, __shfl_xor(mnv, off, 64));
            mxv = fmaxf(mxv, __shfl_xor(mxv, off, 64));
            sv += __shfl_xor(sv, off, 64);
        }
        if (lane == 0) {
            pmin[blockIdx.x] = mnv;
            pmax[blockIdx.x] = mxv;
            psum[blockIdx.x] = sv;               // f32 block partial (fixed order)
        }
    }
}

// ---------------- K2: redundant scalar reduce + ratio / importance / mask ------
__global__ __launch_bounds__(256) void k_output(const float* __restrict__ resized,
                                                const float* __restrict__ pmin,
                                                const float* __restrict__ pmax,
                                                const float* __restrict__ psum,
                                                int nblk1,
                                                float* __restrict__ out,
                                                int npair, int tpp, int num_tokens) {
    // redundant reduction of partials (fixed order -> deterministic & identical
    // in every block; partials are L2/L3-resident). f64 sum: same order as the
    // previously-passing k_scalars.
    int t = threadIdx.x;
    float  mn = INFINITY, mx = -INFINITY;
    double s  = 0.0;
    for (int i = t; i < nblk1; i += 256) {
        mn = fminf(mn, pmin[i]);
        mx = fmaxf(mx, pmax[i]);
        s += (double)psum[i];
    }
    #pragma unroll
    for (int off = 32; off; off >>= 1) {
        mn = fminf(mn, __shfl_xor(mn, off, 64));
        mx = fmaxf(mx, __shfl_xor(mx, off, 64));
        s += __shfl_xor(s, off, 64);
    }
    __shared__ float  smn[4], smx[4];
    __shared__ double ssm[4];
    __shared__ float  sc3[3];
    int wid = t >> 6, lane = t & 63;
    if (lane == 0) { smn[wid] = mn; smx[wid] = mx; ssm[wid] = s; }
    __syncthreads();
    if (t == 0) {
        mn = fminf(fminf(smn[0], smn[1]), fminf(smn[2], smn[3]));
        mx = fmaxf(fmaxf(smx[0], smx[1]), fmaxf(smx[2], smx[3]));
        s  = ssm[0] + ssm[1] + ssm[2] + ssm[3];
        // reference f32 semantics: denom = (m_max - m_min) + 1e-6 in f32
        float denom = __fadd_rn(__fsub_rn(mx, mn), 1e-6f);
        double mean     = s / (double)npair;
        double avg_norm = (mean - (double)mn) / (double)denom;
        double cur_avg  = 0.25 + 0.75 * avg_norm;          // mean of compression_ratio
        sc3[0] = mn;
        sc3[1] = denom;
        sc3[2] = (float)(0.5 / (cur_avg + 1e-6));
    }
    __syncthreads();
    const float fmn = sc3[0], fden = sc3[1], fscale = sc3[2];

    // per-pair outputs
    int base = blockIdx.x * 256;
    int g = base + t;
    __shared__ int      kk[256];
    __shared__ unsigned kbase[256];   // element offset of this pair's mask row
    int k = 0;
    unsigned kb = 0;
    if (g < npair) {
        float r = resized[g];
        // emulate np elementwise f32 rounding: no fma contraction
        float norm   = __fdiv_rn(__fsub_rn(r, fmn), fden);
        float ratio0 = __fadd_rn(0.25f, __fmul_rn(0.75f, norm));
        float sc     = __fmul_rn(ratio0, fscale);
        float ratio  = fminf(fmaxf(sc, 0.25f), 1.0f);
        k = (int)rintf(__fmul_rn(ratio, (float)tpp));   // jnp.round = half-to-even
        k = min(max(k, 1), tpp);
        out[g]         = ratio;   // compression_ratio
        out[npair + g] = norm;    // importance_scores
        unsigned b = (unsigned)g / HW2;
        unsigned p = (unsigned)g - b * HW2;
        kb = b * (unsigned)num_tokens + p * (unsigned)tpp;
    }
    kk[t]    = k;
    kbase[t] = kb;
    __syncthreads();

    float* mask = out + 2 * (size_t)npair;
    int nprs = min(256, npair - base);
    if ((tpp & 3) == 0) {
        int tq = tpp >> 2;
        int total4 = nprs * tq;
        for (int i = t; i < total4; i += 256) {
            int pr = (unsigned)i / (unsigned)tq;
            int wi = (i - pr * tq) * 4;
            int kv = kk[pr];
            float4 m;
            m.x = (wi     < kv) ? 1.0f : 0.0f;
            m.y = (wi + 1 < kv) ? 1.0f : 0.0f;
            m.z = (wi + 2 < kv) ? 1.0f : 0.0f;
            m.w = (wi + 3 < kv) ? 1.0f : 0.0f;
            *(float4*)(mask + (size_t)kbase[pr] + wi) = m;
        }
    } else {
        int total = nprs * tpp;
        for (int i = t; i < total; i += 256) {
            int pr = (unsigned)i / (unsigned)tpp;
            int wi = i - pr * tpp;
            mask[(size_t)kbase[pr] + wi] = (wi < kk[pr]) ? 1.0f : 0.0f;
        }
    }
}

// ---------------- pad (only if 196*tpp < num_tokens; not hit at these sizes) ----
__global__ void k_pad(float* __restrict__ mask, int B, int num_tokens, int used) {
    int per = num_tokens - used;
    int idx = blockIdx.x * 256 + threadIdx.x;
    int tot = B * per;
    if (idx < tot) {
        int b = idx / per;
        int j = idx - b * per;
        mask[(size_t)b * num_tokens + used + j] = 0.0f;
    }
}

extern "C" void kernel_launch(void* const* d_in, const int* in_sizes, int n_in,
                              void* d_out, int out_size, void* d_ws, size_t ws_size,
                              hipStream_t stream) {
    const float* motion = (const float*)d_in[0];
    int nelem = in_sizes[0];                 // B*1*224*224
    int B     = nelem / IMG2;                // 512
    int npair = B * HW2;                     // 100352
    int num_tokens = (out_size - 2 * npair) / B;   // 6272
    int tpp   = num_tokens / HW2;            // 32

    int nstrips = npair / 14;                // 7168 (strip = 14 patches)
    int nb1 = nstrips / SPB;                 // 3584 (exact: B even)

    // workspace layout (all f32)
    float* resized = (float*)d_ws;
    float* psum = resized + npair;
    float* pmin = psum + nb1;
    float* pmax = pmin + nb1;

    hipLaunchKernelGGL(k_patch_mean, dim3(nb1), dim3(256), 0, stream,
                       motion, resized, pmin, pmax, psum);

    int nb2 = (npair + 255) / 256;           // 392
    hipLaunchKernelGGL(k_output, dim3(nb2), dim3(256), 0, stream,
                       resized, pmin, pmax, psum, nb1,
                       (float*)d_out, npair, tpp, num_tokens);

    int used = HW2 * tpp;
    if (used < num_tokens) {
        int tot = B * (num_tokens - used);
        hipLaunchKernelGGL(k_pad, dim3((tot + 255) / 256), dim3(256), 0, stream,
                           (float*)d_out + 2 * (size_t)npair, B, num_tokens, used);
    }
}

// Round 12
// 25.589 us; speedup vs baseline: 1.2016x; 1.2016x over previous
//
#include <hip/hip_runtime.h>
#include <math.h>

#define HW2   196      // 14*14
#define IMG   224
#define IMG2  (224*224)
#define SPB   4        // strips per block (4 waves, one strip per wave)

typedef float f32x4 __attribute__((ext_vector_type(4)));

// ---------------- K1: strip-contiguous patch means (best measured variant) ----
// Strip = one patch-row of one image = contiguous 16*224 floats.
// One wave per strip. Lane l<56 owns columns 4l..4l+3: accumulates a private
// float4 over the 16 rows (16 unrolled independent 896B nt-loads, pure
// load+fadd). Tail: 3 shuffles -> 14 patch means -> LDS; wave 0 alone does
// one 56-wide f32 butterfly for the block's {min,max,sum} partials.
__global__ __launch_bounds__(256) void k_patch_mean(const float* __restrict__ in,
                                                    float* __restrict__ resized,
                                                    float* __restrict__ pmin,
                                                    float* __restrict__ pmax,
                                                    float* __restrict__ psum,
                                                    int nstrips) {
    const int t    = threadIdx.x;
    const int wid  = t >> 6;
    const int lane = t & 63;
    const int s    = blockIdx.x * SPB + wid;

    f32x4 acc = (f32x4)(0.f);
    if (s < nstrips && lane < 56) {
        const f32x4* strip = (const f32x4*)(in + (size_t)s * (16 * IMG)) + lane;
        #pragma unroll
        for (int r = 0; r < 16; ++r) {
            f32x4 v = __builtin_nontemporal_load(&strip[r * 56]);
            acc += v;
        }
    }
    // once-per-strip cross-lane: column sums -> patch sums at lanes 4p
    float h = (acc.x + acc.y) + (acc.z + acc.w);
    h += __shfl_xor(h, 1, 64);
    h += __shfl_xor(h, 2, 64);
    float g = __shfl(h, lane * 4, 64);             // lane p<14 gathers patch p

    __shared__ float means[SPB * 14];
    if (s < nstrips && lane < 14) {
        float mean = g * (1.0f / 256.0f);
        resized[s * 14 + lane] = mean;             // contiguous 56B per wave
        means[wid * 14 + lane] = mean;
    }
    __syncthreads();

    if (wid == 0) {                                // wave 0 reduces the block
        float mnv = INFINITY, mxv = -INFINITY, sv = 0.0f;
        if (lane < SPB * 14) {
            int s2 = blockIdx.x * SPB + (lane / 14);
            if (s2 < nstrips) {
                float m = means[lane];
                mnv = m; mxv = m; sv = m;
            }
        }
        #pragma unroll
        for (int off = 32; off; off >>= 1) {
            mnv = fminf(mnv, __shfl_xor(mnv, off, 64));
            mxv = fmaxf(mxv, __shfl_xor(mxv, off, 64));
            sv += __shfl_xor(sv, off, 64);
        }
        if (lane == 0) {
            pmin[blockIdx.x] = mnv;
            pmax[blockIdx.x] = mxv;
            psum[blockIdx.x] = sv;   // f32 block partial (56 values, exact order)
        }
    }
}

// ---------------- K2: redundant scalar prologue + stream-out --------------------
__global__ __launch_bounds__(256) void k_output(const float* __restrict__ resized,
                                                const float* __restrict__ pmin,
                                                const float* __restrict__ pmax,
                                                const float* __restrict__ psum,
                                                int nblk1,
                                                float* __restrict__ out,
                                                int npair, int tpp, int num_tokens) {
    // redundant reduction of partials (fixed order -> deterministic & identical
    // in every block; partials are L2/L3-resident). f64 sum, same order as the
    // previously-passing k_scalars.
    int t = threadIdx.x;
    float  mn = INFINITY, mx = -INFINITY;
    double s  = 0.0;
    for (int i = t; i < nblk1; i += 256) {
        mn = fminf(mn, pmin[i]);
        mx = fmaxf(mx, pmax[i]);
        s += (double)psum[i];
    }
    #pragma unroll
    for (int off = 32; off; off >>= 1) {
        mn = fminf(mn, __shfl_xor(mn, off, 64));
        mx = fmaxf(mx, __shfl_xor(mx, off, 64));
        s += __shfl_xor(s, off, 64);
    }
    __shared__ float  smn[4], smx[4];
    __shared__ double ssm[4];
    __shared__ float  sc3[3];
    int wid = t >> 6, lane = t & 63;
    if (lane == 0) { smn[wid] = mn; smx[wid] = mx; ssm[wid] = s; }
    __syncthreads();
    if (t == 0) {
        mn = fminf(fminf(smn[0], smn[1]), fminf(smn[2], smn[3]));
        mx = fmaxf(fmaxf(smx[0], smx[1]), fmaxf(smx[2], smx[3]));
        s  = ssm[0] + ssm[1] + ssm[2] + ssm[3];
        // reference f32 semantics: denom = (m_max - m_min) + 1e-6 in f32
        float denom = __fadd_rn(__fsub_rn(mx, mn), 1e-6f);
        double mean     = s / (double)npair;
        double avg_norm = (mean - (double)mn) / (double)denom;
        double cur_avg  = 0.25 + 0.75 * avg_norm;          // mean of compression_ratio
        sc3[0] = mn;
        sc3[1] = denom;
        sc3[2] = (float)(0.5 / (cur_avg + 1e-6));
    }
    __syncthreads();
    const float fmn = sc3[0], fden = sc3[1], fscale = sc3[2];

    // per-pair outputs
    int base = blockIdx.x * 256;
    int g = base + t;
    __shared__ int      kk[256];
    __shared__ unsigned kbase[256];   // element offset of this pair's mask row
    int k = 0;
    unsigned kb = 0;
    if (g < npair) {
        float r = resized[g];
        // emulate np elementwise f32 rounding: no fma contraction
        float norm   = __fdiv_rn(__fsub_rn(r, fmn), fden);
        float ratio0 = __fadd_rn(0.25f, __fmul_rn(0.75f, norm));
        float sc     = __fmul_rn(ratio0, fscale);
        float ratio  = fminf(fmaxf(sc, 0.25f), 1.0f);
        k = (int)rintf(__fmul_rn(ratio, (float)tpp));   // jnp.round = half-to-even
        k = min(max(k, 1), tpp);
        __builtin_nontemporal_store(ratio, out + g);          // compression_ratio
        __builtin_nontemporal_store(norm,  out + npair + g);  // importance_scores
        unsigned b = (unsigned)g / HW2;
        unsigned p = (unsigned)g - b * HW2;
        kb = b * (unsigned)num_tokens + p * (unsigned)tpp;
    }
    kk[t]    = k;
    kbase[t] = kb;
    __syncthreads();

    float* mask = out + 2 * (size_t)npair;
    int nprs = min(256, npair - base);
    if ((tpp & 3) == 0) {
        int tq = tpp >> 2;
        int total4 = nprs * tq;
        for (int i = t; i < total4; i += 256) {
            int pr = (unsigned)i / (unsigned)tq;
            int wi = (i - pr * tq) * 4;
            int kv = kk[pr];
            f32x4 m;
            m.x = (wi     < kv) ? 1.0f : 0.0f;
            m.y = (wi + 1 < kv) ? 1.0f : 0.0f;
            m.z = (wi + 2 < kv) ? 1.0f : 0.0f;
            m.w = (wi + 3 < kv) ? 1.0f : 0.0f;
            __builtin_nontemporal_store(m, (f32x4*)(mask + (size_t)kbase[pr] + wi));
        }
    } else {
        int total = nprs * tpp;
        for (int i = t; i < total; i += 256) {
            int pr = (unsigned)i / (unsigned)tpp;
            int wi = i - pr * tpp;
            mask[(size_t)kbase[pr] + wi] = (wi < kk[pr]) ? 1.0f : 0.0f;
        }
    }
}

// ---------------- pad (only if 196*tpp < num_tokens; not hit at these sizes) ----
__global__ void k_pad(float* __restrict__ mask, int B, int num_tokens, int used) {
    int per = num_tokens - used;
    int idx = blockIdx.x * 256 + threadIdx.x;
    int tot = B * per;
    if (idx < tot) {
        int b = idx / per;
        int j = idx - b * per;
        mask[(size_t)b * num_tokens + used + j] = 0.0f;
    }
}

extern "C" void kernel_launch(void* const* d_in, const int* in_sizes, int n_in,
                              void* d_out, int out_size, void* d_ws, size_t ws_size,
                              hipStream_t stream) {
    const float* motion = (const float*)d_in[0];
    int nelem = in_sizes[0];                 // B*1*224*224
    int B     = nelem / IMG2;                // 512
    int npair = B * HW2;                     // 100352
    int num_tokens = (out_size - 2 * npair) / B;   // 6272
    int tpp   = num_tokens / HW2;            // 32

    int nstrips = npair / 14;                // 7168 (strip = 14 patches)
    int nb1 = (nstrips + SPB - 1) / SPB;     // 1792

    // workspace layout (all f32)
    float* resized = (float*)d_ws;
    float* psum = resized + npair;
    float* pmin = psum + nb1;
    float* pmax = pmin + nb1;

    hipLaunchKernelGGL(k_patch_mean, dim3(nb1), dim3(256), 0, stream,
                       motion, resized, pmin, pmax, psum, nstrips);

    int nb2 = (npair + 255) / 256;           // 392
    hipLaunchKernelGGL(k_output, dim3(nb2), dim3(256), 0, stream,
                       resized, pmin, pmax, psum, nb1,
                       (float*)d_out, npair, tpp, num_tokens);

    int used = HW2 * tpp;
    if (used < num_tokens) {
        int tot = B * (num_tokens - used);
        hipLaunchKernelGGL(k_pad, dim3((tot + 255) / 256), dim3(256), 0, stream,
                           (float*)d_out + 2 * (size_t)npair, B, num_tokens, used);
    }
}